// Round 12
// baseline (408.430 us; speedup 1.0000x reference)
//
#include <hip/hip_runtime.h>
#include <hip/hip_fp16.h>

#define N_NODES 100000
#define N_EDGES 1600000
#define N_GRAPHS 1024
#define F_IN 128
#define HDIM 64
#define NCOARSE 391            // dst>>8 buckets
#define NBLK_C 256             // coarse blocks (1024 thr each)
#define EPB 6250               // N_EDGES / NBLK_C
#define NH (NCOARSE * 256)     // 100096: per-(bucket, g=b&7, j=b>>3) histogram
#define NSCN (NH / 256)        // 391 scan blocks

typedef _Float16 half4f __attribute__((ext_vector_type(4)));
typedef float f32x4 __attribute__((ext_vector_type(4)));

// ---------------------------------------------------------------------------
// block 0: wt = W3 @ lin_w (64), bconst = b3 . lin_w; blocks 1..4: zero gsum/gcnt
__global__ __launch_bounds__(256) void wtilde_k(const float* __restrict__ W3,
                                                const float* __restrict__ b3,
                                                const float* __restrict__ lw,
                                                float* __restrict__ wt,
                                                float* __restrict__ bc,
                                                float* __restrict__ gsum,
                                                float* __restrict__ gcnt) {
    if (blockIdx.x == 0) {
        int t = threadIdx.x;
        if (t < 64) {
            float d = 0.0f;
            for (int c = 0; c < 64; ++c) d = fmaf(W3[t * 64 + c], lw[c], d);
            wt[t] = d;
        } else if (t == 64) {
            float d = 0.0f;
            for (int c = 0; c < 64; ++c) d = fmaf(b3[c], lw[c], d);
            bc[0] = d;
        }
    } else {
        int i = (blockIdx.x - 1) * 256 + threadIdx.x;
        if (i < N_GRAPHS) { gsum[i] = 0.0f; gcnt[i] = 0.0f; }
    }
}

// per-block LDS coarse histogram -> H[(c*8+g)*32+j], g=b&7, j=b>>3
__global__ __launch_bounds__(1024) void coarse_hist_k(const int* __restrict__ dst,
                                                      int* __restrict__ H) {
    __shared__ int hist[NCOARSE];
    for (int i = threadIdx.x; i < NCOARSE; i += 1024) hist[i] = 0;
    __syncthreads();
    int b = blockIdx.x;
    int e0 = b * EPB;
    for (int e = e0 + threadIdx.x; e < e0 + EPB; e += 1024)
        atomicAdd(&hist[dst[e] >> 8], 1);
    __syncthreads();
    int g = b & 7, j = b >> 3;
    for (int c = threadIdx.x; c < NCOARSE; c += 1024)
        H[(c * 8 + g) * 32 + j] = hist[c];
}

// ---- 3-kernel exclusive scan of H (100096 elems) -> goff + cbase[c] ----
__global__ __launch_bounds__(256) void scanA_k(const int* __restrict__ H,
                                               int* __restrict__ bsum) {
    __shared__ int sm[256];
    int i = blockIdx.x * 256 + threadIdx.x;
    sm[threadIdx.x] = H[i];
    __syncthreads();
    for (int o = 128; o > 0; o >>= 1) {
        if (threadIdx.x < o) sm[threadIdx.x] += sm[threadIdx.x + o];
        __syncthreads();
    }
    if (threadIdx.x == 0) bsum[blockIdx.x] = sm[0];
}

__global__ __launch_bounds__(1024) void scanB_k(const int* __restrict__ bsum,
                                                int* __restrict__ boff) {
    __shared__ int tsum[1024];
    int t = threadIdx.x;
    int v = (t < NSCN) ? bsum[t] : 0;
    tsum[t] = v;
    __syncthreads();
    for (int o = 1; o < 1024; o <<= 1) {
        int add = (t >= o) ? tsum[t - o] : 0;
        __syncthreads();
        tsum[t] += add;
        __syncthreads();
    }
    if (t < NSCN) boff[t] = tsum[t] - v;
}

__global__ __launch_bounds__(256) void scanC_k(const int* __restrict__ H,
                                               const int* __restrict__ boff,
                                               int* __restrict__ goff,
                                               int* __restrict__ cbase) {
    __shared__ int sm[256];
    int blk = blockIdx.x, t = threadIdx.x;
    int i = blk * 256 + t;
    int v = H[i];
    sm[t] = v;
    __syncthreads();
    for (int o = 1; o < 256; o <<= 1) {
        int add = (t >= o) ? sm[t - o] : 0;
        __syncthreads();
        sm[t] += add;
        __syncthreads();
    }
    int excl = boff[blk] + sm[t] - v;
    goff[i] = excl;
    if (t == 0) cbase[blk] = excl;             // bucket blk starts at i=blk*256
    if (blk == 0 && t == 0) cbase[NCOARSE] = N_EDGES;
}

// coarse scatter, deterministic: LDS cursors from goff; LDS atomics only
__global__ __launch_bounds__(1024) void coarse_scatter_k(const int* __restrict__ src,
                                                         const int* __restrict__ dst,
                                                         const int* __restrict__ goff,
                                                         int* __restrict__ eC) {
    __shared__ int cur[NCOARSE];
    int b = blockIdx.x, t = threadIdx.x, g = b & 7, j = b >> 3;
    for (int c = t; c < NCOARSE; c += 1024)
        cur[c] = goff[(c * 8 + g) * 32 + j];
    __syncthreads();
    int e0 = b * EPB;
    for (int e = e0 + t; e < e0 + EPB; e += 1024) {
        int s = src[e], d = dst[e];
        int pos = atomicAdd(&cur[d >> 8], 1);
        eC[pos] = s | ((d & 255) << 17);
    }
}

// per bucket: node counts (LDS) -> rowptr + dinv
__global__ __launch_bounds__(1024) void bucket_count_k(const int* __restrict__ eC,
                                                       const int* __restrict__ cbase,
                                                       int* __restrict__ rowptr,
                                                       float* __restrict__ dinv) {
    __shared__ int cnt[256];
    __shared__ int sc[256];
    int c = blockIdx.x, t = threadIdx.x;
    if (t < 256) cnt[t] = 0;
    __syncthreads();
    int s0 = cbase[c], s1 = cbase[c + 1];
    for (int e = s0 + t; e < s1; e += 1024)
        atomicAdd(&cnt[(eC[e] >> 17) & 255], 1);
    __syncthreads();
    if (t < 256) sc[t] = cnt[t];
    __syncthreads();
    for (int o = 1; o < 256; o <<= 1) {
        int add = (t >= o && t < 256) ? sc[t - o] : 0;
        __syncthreads();
        if (t < 256) sc[t] += add;
        __syncthreads();
    }
    int node = c * 256 + t;
    if (t < 256 && node < N_NODES) {
        rowptr[node] = s0 + sc[t] - cnt[t];
        dinv[node] = rsqrtf((float)cnt[t] + 1.0f);  // +1 self loop
    }
    if (node == N_NODES - 1) rowptr[N_NODES] = s1;
}

// per bucket: node-sort the bucket segment; src index only (4B/edge)
__global__ __launch_bounds__(1024) void bucket_scatter_k(const int* __restrict__ eC,
                                                         const int* __restrict__ cbase,
                                                         const int* __restrict__ rowptr,
                                                         int* __restrict__ es) {
    __shared__ int cur[256];
    int c = blockIdx.x, t = threadIdx.x;
    int node = c * 256 + t;
    if (t < 256) cur[t] = (node < N_NODES) ? rowptr[node] : 0;
    __syncthreads();
    int s0 = cbase[c], s1 = cbase[c + 1];
    for (int e = s0 + t; e < s1; e += 1024) {
        int u = eC[e];
        int pos = atomicAdd(&cur[(u >> 17) & 255], 1);
        es[pos] = u & 0x1FFFF;
    }
}

// ---------------------------------------------------------------------------
// MFMA GEMM with dinv-prescaled output: out[r][c] = (sum_k A[r][k]*W[k][c])*dinv[r]
template <int K>
__global__ __launch_bounds__(256) void gemm_k(const float* __restrict__ A,
                                              const float* __restrict__ W,
                                              const float* __restrict__ dinv,
                                              __half* __restrict__ out) {
    constexpr int PITCH = K + 24;
    __shared__ __align__(16) _Float16 Wt[64 * PITCH];
    for (int i = threadIdx.x; i < K * 64; i += 256) {
        int k = i >> 6, c = i & 63;
        Wt[c * PITCH + k] = (_Float16)W[i];
    }
    __syncthreads();

    const int lane = threadIdx.x & 63;
    const int wid  = threadIdx.x >> 6;
    const int cl   = lane & 15;
    const int kq   = lane >> 4;
    const int c0   = wid * 16;
    const int r0   = blockIdx.x * 64;

    f32x4 acc[4] = {};
#pragma unroll
    for (int ks = 0; ks < K / 16; ++ks) {
        const int kbase = ks * 16 + kq * 4;
        const half4f bf = *(const half4f*)&Wt[(c0 + cl) * PITCH + kbase];
#pragma unroll
        for (int m = 0; m < 4; ++m) {
            int r = r0 + m * 16 + cl;
            float4 a4 = (r < N_NODES)
                            ? *(const float4*)(A + (size_t)r * K + kbase)
                            : make_float4(0.f, 0.f, 0.f, 0.f);
            half4f af = {(_Float16)a4.x, (_Float16)a4.y,
                         (_Float16)a4.z, (_Float16)a4.w};
            acc[m] = __builtin_amdgcn_mfma_f32_16x16x16f16(af, bf, acc[m], 0, 0, 0);
        }
    }
#pragma unroll
    for (int m = 0; m < 4; ++m) {
        int rbase = r0 + m * 16 + kq * 4;
#pragma unroll
        for (int reg = 0; reg < 4; ++reg) {
            int r = rbase + reg;
            if (r < N_NODES)
                out[(size_t)r * HDIM + c0 + cl] =
                    __float2half(acc[m][reg] * dinv[r]);
        }
    }
}

// ---------------------------------------------------------------------------
// one wave per dst node. hw rows are dinv-prescaled -> inner loop is PURE adds:
// acc = b + dv*(hw'[node] + sum hw'[src]).  EMIT_S: ss[node] = (relu.wt)*dv.
template <bool RELU_OUT, bool EMIT_S>
__global__ __launch_bounds__(256) void agg_k(const int* __restrict__ rowptr,
                                             const int* __restrict__ es,
                                             const float* __restrict__ dinv,
                                             const __half* __restrict__ hw,
                                             const float* __restrict__ b,
                                             float* __restrict__ h,
                                             const float* __restrict__ wt,
                                             float* __restrict__ ss) {
    const int lane = threadIdx.x & 63;
    int node = (blockIdx.x * 256 + threadIdx.x) >> 6;
    if (node >= N_NODES) return;
    int e0 = rowptr[node], e1 = rowptr[node + 1];
    float dv = dinv[node];
    float acc = __half2float(hw[(size_t)node * HDIM + lane]);

    int e = e0;
    while ((e & 3) && e < e1) {  // align to 16B
        acc += __half2float(hw[(size_t)es[e] * HDIM + lane]);
        ++e;
    }
    for (; e + 8 <= e1; e += 8) {
        int4 ma = *(const int4*)(es + e);
        int4 mb = *(const int4*)(es + e + 4);
        float v0 = __half2float(hw[(size_t)ma.x * HDIM + lane]);
        float v1 = __half2float(hw[(size_t)ma.y * HDIM + lane]);
        float v2 = __half2float(hw[(size_t)ma.z * HDIM + lane]);
        float v3 = __half2float(hw[(size_t)ma.w * HDIM + lane]);
        float v4 = __half2float(hw[(size_t)mb.x * HDIM + lane]);
        float v5 = __half2float(hw[(size_t)mb.y * HDIM + lane]);
        float v6 = __half2float(hw[(size_t)mb.z * HDIM + lane]);
        float v7 = __half2float(hw[(size_t)mb.w * HDIM + lane]);
        acc += v0 + v1 + v2 + v3 + v4 + v5 + v6 + v7;
    }
    for (; e < e1; ++e)
        acc += __half2float(hw[(size_t)es[e] * HDIM + lane]);

    acc = b[lane] + dv * acc;
    if (RELU_OUT) acc = fmaxf(acc, 0.0f);
    if constexpr (EMIT_S) {
        float d = acc * wt[lane];
        for (int o = 32; o > 0; o >>= 1) d += __shfl_down(d, o);
        if (lane == 0) ss[node] = d * dv;
    } else {
        h[(size_t)node * HDIM + lane] = acc;
    }
}

// ---------------------------------------------------------------------------
// layer-3 scalar aggregation + fused mean-pool. ss is dinv-prescaled:
// nodeval = bc + dv*(ss[i] + sum ss[src]). 4 threads per node (edge quarters).
__global__ __launch_bounds__(256) void agg3s_k(const int* __restrict__ rowptr,
                                               const int* __restrict__ es,
                                               const float* __restrict__ dinv,
                                               const float* __restrict__ ss,
                                               const int* __restrict__ batch,
                                               const float* __restrict__ bc,
                                               float* __restrict__ gsum,
                                               float* __restrict__ gcnt) {
    int t = blockIdx.x * 256 + threadIdx.x;
    int i = t >> 2, q = t & 3;
    bool act = i < N_NODES;
    float contrib = 0.0f;
    int g = -1;
    if (act) {
        g = batch[i];
        float dv = dinv[i];
        int e0 = rowptr[i], len = rowptr[i + 1] - e0;
        int qa = e0 + ((len * q) >> 2);
        int qb = e0 + ((len * (q + 1)) >> 2);
        float acc = (q == 0) ? ss[i] : 0.0f;
#pragma unroll 4
        for (int e = qa; e < qb; ++e) acc += ss[es[e]];
        contrib = dv * acc + ((q == 0) ? bc[0] : 0.0f);
    }
    int g0 = __shfl(g, 0);
    bool uni = (__ballot(act && (g == g0)) == ~0ULL);
    if (uni) {
        for (int o = 32; o > 0; o >>= 1) contrib += __shfl_down(contrib, o);
        if ((threadIdx.x & 63) == 0) {
            atomicAdd(&gsum[g0], contrib);
            atomicAdd(&gcnt[g0], 16.0f);   // 16 nodes per uniform wave
        }
    } else if (act) {
        atomicAdd(&gsum[g], contrib);
        if (q == 0) atomicAdd(&gcnt[g], 1.0f);
    }
}

__global__ void final_k(float* __restrict__ out, const float* __restrict__ gsum,
                        const float* __restrict__ gcnt, const float* __restrict__ lb) {
    int g = blockIdx.x * blockDim.x + threadIdx.x;
    if (g < N_GRAPHS) out[g] = gsum[g] / fmaxf(gcnt[g], 1.0f) + lb[0];
}

// ---------------------------------------------------------------------------
extern "C" void kernel_launch(void* const* d_in, const int* in_sizes, int n_in,
                              void* d_out, int out_size, void* d_ws, size_t ws_size,
                              hipStream_t stream) {
    const float* x     = (const float*)d_in[0];
    const int*   eidx  = (const int*)d_in[1];   // [2, E] int32
    const int*   batch = (const int*)d_in[3];
    const float* W1 = (const float*)d_in[4];
    const float* b1 = (const float*)d_in[5];
    const float* W2 = (const float*)d_in[6];
    const float* b2 = (const float*)d_in[7];
    const float* W3 = (const float*)d_in[8];
    const float* b3 = (const float*)d_in[9];
    const float* lin_w = (const float*)d_in[10];
    const float* lin_b = (const float*)d_in[11];
    float* out = (float*)d_out;

    const int* src = eidx;
    const int* dst = eidx + N_EDGES;

    float*  ws     = (float*)d_ws;
    float*  dinv   = ws;                         // 100352 f
    int*    rowptr = (int*)(ws + 100352);        // 100352 i (needs 100001)
    int*    cbase  = rowptr + 100352;            // 512 (needs 392)
    int*    bsum   = cbase + 512;                // 512 (needs 391)
    int*    boff   = bsum + 512;                 // 512
    int*    H      = boff + 512;                 // 100352 (needs 100096)
    int*    goff   = H + 100352;                 // 100352
    int*    es     = goff + 100352;              // 1.6M i, 16B-aligned
    __half* bufH   = (__half*)(es + N_EDGES);    // 6.4M halfs (12.8 MB) gemm-out
    float*  bufF   = (float*)(bufH + 6400000);   // 6.4M f (25.6 MB) agg1-out
    float*  gsum   = bufF + 6400000;             // 1024
    float*  gcnt   = gsum + 1024;                // 1024
    float*  wt     = gcnt + 1024;                // 128 (needs 64)
    float*  bc     = wt + 128;                   // 16 (needs 1)
    float*  ss     = bc + 16;                    // 100352   (~48 MB total)
    int*    eC     = (int*)bufH;                 // 1.6M i, aliases bufH

    // ---- precompute + CSR build (deterministic; zero global atomics) ----
    wtilde_k<<<5, 256, 0, stream>>>(W3, b3, lin_w, wt, bc, gsum, gcnt);
    coarse_hist_k<<<NBLK_C, 1024, 0, stream>>>(dst, H);
    scanA_k<<<NSCN, 256, 0, stream>>>(H, bsum);
    scanB_k<<<1, 1024, 0, stream>>>(bsum, boff);
    scanC_k<<<NSCN, 256, 0, stream>>>(H, boff, goff, cbase);
    coarse_scatter_k<<<NBLK_C, 1024, 0, stream>>>(src, dst, goff, eC);
    bucket_count_k<<<NCOARSE, 1024, 0, stream>>>(eC, cbase, rowptr, dinv);
    bucket_scatter_k<<<NCOARSE, 1024, 0, stream>>>(eC, cbase, rowptr, es);

    // ---- layer 1 ----
    gemm_k<F_IN><<<1563, 256, 0, stream>>>(x, W1, dinv, bufH);
    agg_k<true, false><<<25000, 256, 0, stream>>>(rowptr, es, dinv, bufH, b1,
                                                  bufF, nullptr, nullptr);
    // ---- layer 2 (s fused into epilogue; h2 never materialized) ----
    gemm_k<HDIM><<<1563, 256, 0, stream>>>(bufF, W2, dinv, bufH);
    agg_k<true, true><<<25000, 256, 0, stream>>>(rowptr, es, dinv, bufH, b2,
                                                 nullptr, wt, ss);
    // ---- layer 3 scalar + fused pool ----
    agg3s_k<<<1563, 256, 0, stream>>>(rowptr, es, dinv, ss, batch, bc, gsum, gcnt);
    final_k<<<(N_GRAPHS + 255) / 256, 256, 0, stream>>>(out, gsum, gcnt, lin_b);
}

// Round 13
// 395.104 us; speedup vs baseline: 1.0337x; 1.0337x over previous
//
#include <hip/hip_runtime.h>
#include <hip/hip_fp16.h>

#define N_NODES 100000
#define N_EDGES 1600000
#define N_GRAPHS 1024
#define F_IN 128
#define HDIM 64
#define NCOARSE 391            // dst>>8 buckets
#define NBLK_C 256             // coarse blocks (1024 thr each)
#define EPB 6250               // N_EDGES / NBLK_C
#define NH (NCOARSE * 256)     // 100096: per-(bucket, g=b&7, j=b>>3) histogram
#define NSCN (NH / 256)        // 391 scan blocks

typedef _Float16 half4f __attribute__((ext_vector_type(4)));
typedef float f32x4 __attribute__((ext_vector_type(4)));

// ---------------------------------------------------------------------------
// block 0: wt = W3 @ lin_w (64), bconst = b3 . lin_w; blocks 1..4: zero gsum/gcnt
__global__ __launch_bounds__(256) void wtilde_k(const float* __restrict__ W3,
                                                const float* __restrict__ b3,
                                                const float* __restrict__ lw,
                                                float* __restrict__ wt,
                                                float* __restrict__ bc,
                                                float* __restrict__ gsum,
                                                float* __restrict__ gcnt) {
    if (blockIdx.x == 0) {
        int t = threadIdx.x;
        if (t < 64) {
            float d = 0.0f;
            for (int c = 0; c < 64; ++c) d = fmaf(W3[t * 64 + c], lw[c], d);
            wt[t] = d;
        } else if (t == 64) {
            float d = 0.0f;
            for (int c = 0; c < 64; ++c) d = fmaf(b3[c], lw[c], d);
            bc[0] = d;
        }
    } else {
        int i = (blockIdx.x - 1) * 256 + threadIdx.x;
        if (i < N_GRAPHS) { gsum[i] = 0.0f; gcnt[i] = 0.0f; }
    }
}

// per-block LDS coarse histogram -> H[(c*8+g)*32+j], g=b&7, j=b>>3
__global__ __launch_bounds__(1024) void coarse_hist_k(const int* __restrict__ dst,
                                                      int* __restrict__ H) {
    __shared__ int hist[NCOARSE];
    for (int i = threadIdx.x; i < NCOARSE; i += 1024) hist[i] = 0;
    __syncthreads();
    int b = blockIdx.x;
    int e0 = b * EPB;
    for (int e = e0 + threadIdx.x; e < e0 + EPB; e += 1024)
        atomicAdd(&hist[dst[e] >> 8], 1);
    __syncthreads();
    int g = b & 7, j = b >> 3;
    for (int c = threadIdx.x; c < NCOARSE; c += 1024)
        H[(c * 8 + g) * 32 + j] = hist[c];
}

// ---- 3-kernel exclusive scan of H (100096 elems) -> goff + cbase[c] ----
__global__ __launch_bounds__(256) void scanA_k(const int* __restrict__ H,
                                               int* __restrict__ bsum) {
    __shared__ int sm[256];
    int i = blockIdx.x * 256 + threadIdx.x;
    sm[threadIdx.x] = H[i];
    __syncthreads();
    for (int o = 128; o > 0; o >>= 1) {
        if (threadIdx.x < o) sm[threadIdx.x] += sm[threadIdx.x + o];
        __syncthreads();
    }
    if (threadIdx.x == 0) bsum[blockIdx.x] = sm[0];
}

__global__ __launch_bounds__(1024) void scanB_k(const int* __restrict__ bsum,
                                                int* __restrict__ boff) {
    __shared__ int tsum[1024];
    int t = threadIdx.x;
    int v = (t < NSCN) ? bsum[t] : 0;
    tsum[t] = v;
    __syncthreads();
    for (int o = 1; o < 1024; o <<= 1) {
        int add = (t >= o) ? tsum[t - o] : 0;
        __syncthreads();
        tsum[t] += add;
        __syncthreads();
    }
    if (t < NSCN) boff[t] = tsum[t] - v;
}

__global__ __launch_bounds__(256) void scanC_k(const int* __restrict__ H,
                                               const int* __restrict__ boff,
                                               int* __restrict__ goff,
                                               int* __restrict__ cbase) {
    __shared__ int sm[256];
    int blk = blockIdx.x, t = threadIdx.x;
    int i = blk * 256 + t;
    int v = H[i];
    sm[t] = v;
    __syncthreads();
    for (int o = 1; o < 256; o <<= 1) {
        int add = (t >= o) ? sm[t - o] : 0;
        __syncthreads();
        sm[t] += add;
        __syncthreads();
    }
    int excl = boff[blk] + sm[t] - v;
    goff[i] = excl;
    if (t == 0) cbase[blk] = excl;
    if (blk == 0 && t == 0) cbase[NCOARSE] = N_EDGES;
}

// coarse scatter, deterministic: LDS cursors from goff; LDS atomics only
__global__ __launch_bounds__(1024) void coarse_scatter_k(const int* __restrict__ src,
                                                         const int* __restrict__ dst,
                                                         const int* __restrict__ goff,
                                                         int* __restrict__ eC) {
    __shared__ int cur[NCOARSE];
    int b = blockIdx.x, t = threadIdx.x, g = b & 7, j = b >> 3;
    for (int c = t; c < NCOARSE; c += 1024)
        cur[c] = goff[(c * 8 + g) * 32 + j];
    __syncthreads();
    int e0 = b * EPB;
    for (int e = e0 + t; e < e0 + EPB; e += 1024) {
        int s = src[e], d = dst[e];
        int pos = atomicAdd(&cur[d >> 8], 1);
        eC[pos] = s | ((d & 255) << 17);
    }
}

// per bucket: node counts (LDS) -> rowptr + dinv
__global__ __launch_bounds__(1024) void bucket_count_k(const int* __restrict__ eC,
                                                       const int* __restrict__ cbase,
                                                       int* __restrict__ rowptr,
                                                       float* __restrict__ dinv) {
    __shared__ int cnt[256];
    __shared__ int sc[256];
    int c = blockIdx.x, t = threadIdx.x;
    if (t < 256) cnt[t] = 0;
    __syncthreads();
    int s0 = cbase[c], s1 = cbase[c + 1];
    for (int e = s0 + t; e < s1; e += 1024)
        atomicAdd(&cnt[(eC[e] >> 17) & 255], 1);
    __syncthreads();
    if (t < 256) sc[t] = cnt[t];
    __syncthreads();
    for (int o = 1; o < 256; o <<= 1) {
        int add = (t >= o && t < 256) ? sc[t - o] : 0;
        __syncthreads();
        if (t < 256) sc[t] += add;
        __syncthreads();
    }
    int node = c * 256 + t;
    if (t < 256 && node < N_NODES) {
        rowptr[node] = s0 + sc[t] - cnt[t];
        dinv[node] = rsqrtf((float)cnt[t] + 1.0f);  // +1 self loop
    }
    if (node == N_NODES - 1) rowptr[N_NODES] = s1;
}

// per bucket: node-sort the bucket segment; src index only (4B/edge)
__global__ __launch_bounds__(1024) void bucket_scatter_k(const int* __restrict__ eC,
                                                         const int* __restrict__ cbase,
                                                         const int* __restrict__ rowptr,
                                                         int* __restrict__ es) {
    __shared__ int cur[256];
    int c = blockIdx.x, t = threadIdx.x;
    int node = c * 256 + t;
    if (t < 256) cur[t] = (node < N_NODES) ? rowptr[node] : 0;
    __syncthreads();
    int s0 = cbase[c], s1 = cbase[c + 1];
    for (int e = s0 + t; e < s1; e += 1024) {
        int u = eC[e];
        int pos = atomicAdd(&cur[(u >> 17) & 255], 1);
        es[pos] = u & 0x1FFFF;
    }
}

// ---------------------------------------------------------------------------
// MFMA GEMM with dinv-prescaled fp16 output; A type templated (fp32 or fp16).
template <int K, typename AT>
__global__ __launch_bounds__(256) void gemm_k(const AT* __restrict__ A,
                                              const float* __restrict__ W,
                                              const float* __restrict__ dinv,
                                              _Float16* __restrict__ out) {
    constexpr int PITCH = K + 24;
    __shared__ __align__(16) _Float16 Wt[64 * PITCH];
    for (int i = threadIdx.x; i < K * 64; i += 256) {
        int k = i >> 6, c = i & 63;
        Wt[c * PITCH + k] = (_Float16)W[i];
    }
    __syncthreads();

    const int lane = threadIdx.x & 63;
    const int wid  = threadIdx.x >> 6;
    const int cl   = lane & 15;
    const int kq   = lane >> 4;
    const int c0   = wid * 16;
    const int r0   = blockIdx.x * 64;

    f32x4 acc[4] = {};
#pragma unroll
    for (int ks = 0; ks < K / 16; ++ks) {
        const int kbase = ks * 16 + kq * 4;
        const half4f bf = *(const half4f*)&Wt[(c0 + cl) * PITCH + kbase];
#pragma unroll
        for (int m = 0; m < 4; ++m) {
            int r = r0 + m * 16 + cl;
            half4f af;
            if (r < N_NODES) {
                if constexpr (sizeof(AT) == 4) {
                    float4 a4 = *(const float4*)(A + (size_t)r * K + kbase);
                    af = half4f{(_Float16)a4.x, (_Float16)a4.y,
                                (_Float16)a4.z, (_Float16)a4.w};
                } else {
                    af = *(const half4f*)(A + (size_t)r * K + kbase);
                }
            } else {
                af = half4f{0, 0, 0, 0};
            }
            acc[m] = __builtin_amdgcn_mfma_f32_16x16x16f16(af, bf, acc[m], 0, 0, 0);
        }
    }
#pragma unroll
    for (int m = 0; m < 4; ++m) {
        int rbase = r0 + m * 16 + kq * 4;
#pragma unroll
        for (int reg = 0; reg < 4; ++reg) {
            int r = rbase + reg;
            if (r < N_NODES)
                out[(size_t)r * HDIM + c0 + cl] =
                    (_Float16)(acc[m][reg] * dinv[r]);
        }
    }
}

// ---------------------------------------------------------------------------
// one wave per dst node. hw rows dinv-prescaled -> pure adds; 16 gathers in
// flight per iteration (latency cover). EMIT_S: ss[node]=(relu.wt)*dv, no h.
// Otherwise h output is fp16 (feeds gemm2 A directly).
template <bool EMIT_S>
__global__ __launch_bounds__(256) void agg_k(const int* __restrict__ rowptr,
                                             const int* __restrict__ es,
                                             const float* __restrict__ dinv,
                                             const _Float16* __restrict__ hw,
                                             const float* __restrict__ b,
                                             _Float16* __restrict__ h,
                                             const float* __restrict__ wt,
                                             float* __restrict__ ss) {
    const int lane = threadIdx.x & 63;
    int node = (blockIdx.x * 256 + threadIdx.x) >> 6;
    if (node >= N_NODES) return;
    int e0 = rowptr[node], e1 = rowptr[node + 1];
    float dv = dinv[node];
    float acc = (float)hw[(size_t)node * HDIM + lane];

    int e = e0;
    while ((e & 3) && e < e1) {  // align to 16B
        acc += (float)hw[(size_t)es[e] * HDIM + lane];
        ++e;
    }
    for (; e + 16 <= e1; e += 16) {
        int4 a0 = *(const int4*)(es + e);
        int4 a1 = *(const int4*)(es + e + 4);
        int4 a2 = *(const int4*)(es + e + 8);
        int4 a3 = *(const int4*)(es + e + 12);
        float v0 = (float)hw[(size_t)a0.x * HDIM + lane];
        float v1 = (float)hw[(size_t)a0.y * HDIM + lane];
        float v2 = (float)hw[(size_t)a0.z * HDIM + lane];
        float v3 = (float)hw[(size_t)a0.w * HDIM + lane];
        float v4 = (float)hw[(size_t)a1.x * HDIM + lane];
        float v5 = (float)hw[(size_t)a1.y * HDIM + lane];
        float v6 = (float)hw[(size_t)a1.z * HDIM + lane];
        float v7 = (float)hw[(size_t)a1.w * HDIM + lane];
        float v8 = (float)hw[(size_t)a2.x * HDIM + lane];
        float v9 = (float)hw[(size_t)a2.y * HDIM + lane];
        float va = (float)hw[(size_t)a2.z * HDIM + lane];
        float vb = (float)hw[(size_t)a2.w * HDIM + lane];
        float vc = (float)hw[(size_t)a3.x * HDIM + lane];
        float vd = (float)hw[(size_t)a3.y * HDIM + lane];
        float ve = (float)hw[(size_t)a3.z * HDIM + lane];
        float vf = (float)hw[(size_t)a3.w * HDIM + lane];
        acc += ((v0 + v1) + (v2 + v3)) + ((v4 + v5) + (v6 + v7)) +
               ((v8 + v9) + (va + vb)) + ((vc + vd) + (ve + vf));
    }
    for (; e + 4 <= e1; e += 4) {
        int4 a0 = *(const int4*)(es + e);
        float v0 = (float)hw[(size_t)a0.x * HDIM + lane];
        float v1 = (float)hw[(size_t)a0.y * HDIM + lane];
        float v2 = (float)hw[(size_t)a0.z * HDIM + lane];
        float v3 = (float)hw[(size_t)a0.w * HDIM + lane];
        acc += (v0 + v1) + (v2 + v3);
    }
    for (; e < e1; ++e)
        acc += (float)hw[(size_t)es[e] * HDIM + lane];

    acc = fmaxf(b[lane] + dv * acc, 0.0f);  // relu (both layers 1,2)
    if constexpr (EMIT_S) {
        float d = acc * wt[lane];
        for (int o = 32; o > 0; o >>= 1) d += __shfl_down(d, o);
        if (lane == 0) ss[node] = d * dv;
    } else {
        h[(size_t)node * HDIM + lane] = (_Float16)acc;
    }
}

// ---------------------------------------------------------------------------
// layer-3 scalar aggregation + fused mean-pool; 4 threads per node.
__global__ __launch_bounds__(256) void agg3s_k(const int* __restrict__ rowptr,
                                               const int* __restrict__ es,
                                               const float* __restrict__ dinv,
                                               const float* __restrict__ ss,
                                               const int* __restrict__ batch,
                                               const float* __restrict__ bc,
                                               float* __restrict__ gsum,
                                               float* __restrict__ gcnt) {
    int t = blockIdx.x * 256 + threadIdx.x;
    int i = t >> 2, q = t & 3;
    bool act = i < N_NODES;
    float contrib = 0.0f;
    int g = -1;
    if (act) {
        g = batch[i];
        float dv = dinv[i];
        int e0 = rowptr[i], len = rowptr[i + 1] - e0;
        int qa = e0 + ((len * q) >> 2);
        int qb = e0 + ((len * (q + 1)) >> 2);
        float acc = (q == 0) ? ss[i] : 0.0f;
#pragma unroll 4
        for (int e = qa; e < qb; ++e) acc += ss[es[e]];
        contrib = dv * acc + ((q == 0) ? bc[0] : 0.0f);
    }
    int g0 = __shfl(g, 0);
    bool uni = (__ballot(act && (g == g0)) == ~0ULL);
    if (uni) {
        for (int o = 32; o > 0; o >>= 1) contrib += __shfl_down(contrib, o);
        if ((threadIdx.x & 63) == 0) {
            atomicAdd(&gsum[g0], contrib);
            atomicAdd(&gcnt[g0], 16.0f);
        }
    } else if (act) {
        atomicAdd(&gsum[g], contrib);
        if (q == 0) atomicAdd(&gcnt[g], 1.0f);
    }
}

__global__ void final_k(float* __restrict__ out, const float* __restrict__ gsum,
                        const float* __restrict__ gcnt, const float* __restrict__ lb) {
    int g = blockIdx.x * blockDim.x + threadIdx.x;
    if (g < N_GRAPHS) out[g] = gsum[g] / fmaxf(gcnt[g], 1.0f) + lb[0];
}

// ---------------------------------------------------------------------------
extern "C" void kernel_launch(void* const* d_in, const int* in_sizes, int n_in,
                              void* d_out, int out_size, void* d_ws, size_t ws_size,
                              hipStream_t stream) {
    const float* x     = (const float*)d_in[0];
    const int*   eidx  = (const int*)d_in[1];   // [2, E] int32
    const int*   batch = (const int*)d_in[3];
    const float* W1 = (const float*)d_in[4];
    const float* b1 = (const float*)d_in[5];
    const float* W2 = (const float*)d_in[6];
    const float* b2 = (const float*)d_in[7];
    const float* W3 = (const float*)d_in[8];
    const float* b3 = (const float*)d_in[9];
    const float* lin_w = (const float*)d_in[10];
    const float* lin_b = (const float*)d_in[11];
    float* out = (float*)d_out;

    const int* src = eidx;
    const int* dst = eidx + N_EDGES;

    float*    ws     = (float*)d_ws;
    float*    dinv   = ws;                          // 100352 f
    int*      rowptr = (int*)(ws + 100352);         // 100352 i
    int*      cbase  = rowptr + 100352;             // 512
    int*      bsum   = cbase + 512;                 // 512
    int*      boff   = bsum + 512;                  // 512
    int*      H      = boff + 512;                  // 100352
    int*      goff   = H + 100352;                  // 100352
    int*      es     = goff + 100352;               // 1.6M i, 16B-aligned
    _Float16* bufH   = (_Float16*)(es + N_EDGES);   // 6.4M halfs gemm-out
    _Float16* bufF   = bufH + 6400000;              // 6.4M halfs agg1-out (fp16)
    float*    gsum   = (float*)(bufF + 6400000);    // 1024
    float*    gcnt   = gsum + 1024;                 // 1024
    float*    wt     = gcnt + 1024;                 // 128
    float*    bc     = wt + 128;                    // 16
    float*    ss     = bc + 16;                     // 100352   (~36 MB total)
    int*      eC     = (int*)bufH;                  // 1.6M i, aliases bufH

    // ---- precompute + CSR build (deterministic; zero global atomics) ----
    wtilde_k<<<5, 256, 0, stream>>>(W3, b3, lin_w, wt, bc, gsum, gcnt);
    coarse_hist_k<<<NBLK_C, 1024, 0, stream>>>(dst, H);
    scanA_k<<<NSCN, 256, 0, stream>>>(H, bsum);
    scanB_k<<<1, 1024, 0, stream>>>(bsum, boff);
    scanC_k<<<NSCN, 256, 0, stream>>>(H, boff, goff, cbase);
    coarse_scatter_k<<<NBLK_C, 1024, 0, stream>>>(src, dst, goff, eC);
    bucket_count_k<<<NCOARSE, 1024, 0, stream>>>(eC, cbase, rowptr, dinv);
    bucket_scatter_k<<<NCOARSE, 1024, 0, stream>>>(eC, cbase, rowptr, es);

    // ---- layer 1 (fp32 x in, fp16 h1 out) ----
    gemm_k<F_IN, float><<<1563, 256, 0, stream>>>(x, W1, dinv, bufH);
    agg_k<false><<<25000, 256, 0, stream>>>(rowptr, es, dinv, bufH, b1,
                                            bufF, nullptr, nullptr);
    // ---- layer 2 (fp16 h1 in; s fused into epilogue) ----
    gemm_k<HDIM, _Float16><<<1563, 256, 0, stream>>>(bufF, W2, dinv, bufH);
    agg_k<true><<<25000, 256, 0, stream>>>(rowptr, es, dinv, bufH, b2,
                                           nullptr, wt, ss);
    // ---- layer 3 scalar + fused pool ----
    agg3s_k<<<1563, 256, 0, stream>>>(rowptr, es, dinv, ss, batch, bc, gsum, gcnt);
    final_k<<<(N_GRAPHS + 255) / 256, 256, 0, stream>>>(out, gsum, gcnt, lin_b);
}

// Round 14
// 391.761 us; speedup vs baseline: 1.0425x; 1.0085x over previous
//
#include <hip/hip_runtime.h>
#include <hip/hip_fp16.h>

#define N_NODES 100000
#define N_EDGES 1600000
#define N_GRAPHS 1024
#define F_IN 128
#define HDIM 64
#define NCOARSE 391            // dst>>8 buckets
#define NBLK_C 256             // coarse blocks (1024 thr each)
#define EPB 6250               // N_EDGES / NBLK_C
#define NH (NCOARSE * 256)     // 100096: per-(bucket, g=b&7, j=b>>3) histogram
#define NSCN (NH / 256)        // 391 scan blocks

typedef _Float16 half4f __attribute__((ext_vector_type(4)));
typedef float f32x4 __attribute__((ext_vector_type(4)));

// ---------------------------------------------------------------------------
// block 0: wt = W3 @ lin_w (64), bconst = b3 . lin_w; blocks 1..4: zero gsum/gcnt
__global__ __launch_bounds__(256) void wtilde_k(const float* __restrict__ W3,
                                                const float* __restrict__ b3,
                                                const float* __restrict__ lw,
                                                float* __restrict__ wt,
                                                float* __restrict__ bc,
                                                float* __restrict__ gsum,
                                                float* __restrict__ gcnt) {
    if (blockIdx.x == 0) {
        int t = threadIdx.x;
        if (t < 64) {
            float d = 0.0f;
            for (int c = 0; c < 64; ++c) d = fmaf(W3[t * 64 + c], lw[c], d);
            wt[t] = d;
        } else if (t == 64) {
            float d = 0.0f;
            for (int c = 0; c < 64; ++c) d = fmaf(b3[c], lw[c], d);
            bc[0] = d;
        }
    } else {
        int i = (blockIdx.x - 1) * 256 + threadIdx.x;
        if (i < N_GRAPHS) { gsum[i] = 0.0f; gcnt[i] = 0.0f; }
    }
}

// per-block LDS coarse histogram -> H[(c*8+g)*32+j], g=b&7, j=b>>3
__global__ __launch_bounds__(1024) void coarse_hist_k(const int* __restrict__ dst,
                                                      int* __restrict__ H) {
    __shared__ int hist[NCOARSE];
    for (int i = threadIdx.x; i < NCOARSE; i += 1024) hist[i] = 0;
    __syncthreads();
    int b = blockIdx.x;
    int e0 = b * EPB;
    for (int e = e0 + threadIdx.x; e < e0 + EPB; e += 1024)
        atomicAdd(&hist[dst[e] >> 8], 1);
    __syncthreads();
    int g = b & 7, j = b >> 3;
    for (int c = threadIdx.x; c < NCOARSE; c += 1024)
        H[(c * 8 + g) * 32 + j] = hist[c];
}

// ---- 3-kernel exclusive scan of H (100096 elems) -> goff + cbase[c] ----
__global__ __launch_bounds__(256) void scanA_k(const int* __restrict__ H,
                                               int* __restrict__ bsum) {
    __shared__ int sm[256];
    int i = blockIdx.x * 256 + threadIdx.x;
    sm[threadIdx.x] = H[i];
    __syncthreads();
    for (int o = 128; o > 0; o >>= 1) {
        if (threadIdx.x < o) sm[threadIdx.x] += sm[threadIdx.x + o];
        __syncthreads();
    }
    if (threadIdx.x == 0) bsum[blockIdx.x] = sm[0];
}

__global__ __launch_bounds__(1024) void scanB_k(const int* __restrict__ bsum,
                                                int* __restrict__ boff) {
    __shared__ int tsum[1024];
    int t = threadIdx.x;
    int v = (t < NSCN) ? bsum[t] : 0;
    tsum[t] = v;
    __syncthreads();
    for (int o = 1; o < 1024; o <<= 1) {
        int add = (t >= o) ? tsum[t - o] : 0;
        __syncthreads();
        tsum[t] += add;
        __syncthreads();
    }
    if (t < NSCN) boff[t] = tsum[t] - v;
}

__global__ __launch_bounds__(256) void scanC_k(const int* __restrict__ H,
                                               const int* __restrict__ boff,
                                               int* __restrict__ goff,
                                               int* __restrict__ cbase) {
    __shared__ int sm[256];
    int blk = blockIdx.x, t = threadIdx.x;
    int i = blk * 256 + t;
    int v = H[i];
    sm[t] = v;
    __syncthreads();
    for (int o = 1; o < 256; o <<= 1) {
        int add = (t >= o) ? sm[t - o] : 0;
        __syncthreads();
        sm[t] += add;
        __syncthreads();
    }
    int excl = boff[blk] + sm[t] - v;
    goff[i] = excl;
    if (t == 0) cbase[blk] = excl;
    if (blk == 0 && t == 0) cbase[NCOARSE] = N_EDGES;
}

// coarse scatter, deterministic: LDS cursors from goff; LDS atomics only
__global__ __launch_bounds__(1024) void coarse_scatter_k(const int* __restrict__ src,
                                                         const int* __restrict__ dst,
                                                         const int* __restrict__ goff,
                                                         int* __restrict__ eC) {
    __shared__ int cur[NCOARSE];
    int b = blockIdx.x, t = threadIdx.x, g = b & 7, j = b >> 3;
    for (int c = t; c < NCOARSE; c += 1024)
        cur[c] = goff[(c * 8 + g) * 32 + j];
    __syncthreads();
    int e0 = b * EPB;
    for (int e = e0 + t; e < e0 + EPB; e += 1024) {
        int s = src[e], d = dst[e];
        int pos = atomicAdd(&cur[d >> 8], 1);
        eC[pos] = s | ((d & 255) << 17);
    }
}

// per bucket: node counts (LDS) -> rowptr + dinv
__global__ __launch_bounds__(1024) void bucket_count_k(const int* __restrict__ eC,
                                                       const int* __restrict__ cbase,
                                                       int* __restrict__ rowptr,
                                                       float* __restrict__ dinv) {
    __shared__ int cnt[256];
    __shared__ int sc[256];
    int c = blockIdx.x, t = threadIdx.x;
    if (t < 256) cnt[t] = 0;
    __syncthreads();
    int s0 = cbase[c], s1 = cbase[c + 1];
    for (int e = s0 + t; e < s1; e += 1024)
        atomicAdd(&cnt[(eC[e] >> 17) & 255], 1);
    __syncthreads();
    if (t < 256) sc[t] = cnt[t];
    __syncthreads();
    for (int o = 1; o < 256; o <<= 1) {
        int add = (t >= o && t < 256) ? sc[t - o] : 0;
        __syncthreads();
        if (t < 256) sc[t] += add;
        __syncthreads();
    }
    int node = c * 256 + t;
    if (t < 256 && node < N_NODES) {
        rowptr[node] = s0 + sc[t] - cnt[t];
        dinv[node] = rsqrtf((float)cnt[t] + 1.0f);  // +1 self loop
    }
    if (node == N_NODES - 1) rowptr[N_NODES] = s1;
}

// per bucket: node-sort the bucket segment; src index only (4B/edge)
__global__ __launch_bounds__(1024) void bucket_scatter_k(const int* __restrict__ eC,
                                                         const int* __restrict__ cbase,
                                                         const int* __restrict__ rowptr,
                                                         int* __restrict__ es) {
    __shared__ int cur[256];
    int c = blockIdx.x, t = threadIdx.x;
    int node = c * 256 + t;
    if (t < 256) cur[t] = (node < N_NODES) ? rowptr[node] : 0;
    __syncthreads();
    int s0 = cbase[c], s1 = cbase[c + 1];
    for (int e = s0 + t; e < s1; e += 1024) {
        int u = eC[e];
        int pos = atomicAdd(&cur[(u >> 17) & 255], 1);
        es[pos] = u & 0x1FFFF;
    }
}

// ---------------------------------------------------------------------------
// MFMA GEMM with dinv-prescaled fp16 output; A type templated (fp32 or fp16).
template <int K, typename AT>
__global__ __launch_bounds__(256) void gemm_k(const AT* __restrict__ A,
                                              const float* __restrict__ W,
                                              const float* __restrict__ dinv,
                                              _Float16* __restrict__ out) {
    constexpr int PITCH = K + 24;
    __shared__ __align__(16) _Float16 Wt[64 * PITCH];
    for (int i = threadIdx.x; i < K * 64; i += 256) {
        int k = i >> 6, c = i & 63;
        Wt[c * PITCH + k] = (_Float16)W[i];
    }
    __syncthreads();

    const int lane = threadIdx.x & 63;
    const int wid  = threadIdx.x >> 6;
    const int cl   = lane & 15;
    const int kq   = lane >> 4;
    const int c0   = wid * 16;
    const int r0   = blockIdx.x * 64;

    f32x4 acc[4] = {};
#pragma unroll
    for (int ks = 0; ks < K / 16; ++ks) {
        const int kbase = ks * 16 + kq * 4;
        const half4f bf = *(const half4f*)&Wt[(c0 + cl) * PITCH + kbase];
#pragma unroll
        for (int m = 0; m < 4; ++m) {
            int r = r0 + m * 16 + cl;
            half4f af;
            if (r < N_NODES) {
                if constexpr (sizeof(AT) == 4) {
                    float4 a4 = *(const float4*)(A + (size_t)r * K + kbase);
                    af = half4f{(_Float16)a4.x, (_Float16)a4.y,
                                (_Float16)a4.z, (_Float16)a4.w};
                } else {
                    af = *(const half4f*)(A + (size_t)r * K + kbase);
                }
            } else {
                af = half4f{0, 0, 0, 0};
            }
            acc[m] = __builtin_amdgcn_mfma_f32_16x16x16f16(af, bf, acc[m], 0, 0, 0);
        }
    }
#pragma unroll
    for (int m = 0; m < 4; ++m) {
        int rbase = r0 + m * 16 + kq * 4;
#pragma unroll
        for (int reg = 0; reg < 4; ++reg) {
            int r = rbase + reg;
            if (r < N_NODES)
                out[(size_t)r * HDIM + c0 + cl] =
                    (_Float16)(acc[m][reg] * dinv[r]);
        }
    }
}

// ---------------------------------------------------------------------------
// Pair-gather agg: one wave per dst node; lanes 0-31 take even edges, 32-63
// odd edges; each lane covers a channel PAIR via one __half2 (4B) load -> one
// gather instruction covers 2 edges. Cross-half combine via shfl_xor(32).
// hw rows dinv-prescaled -> pure adds. EMIT_S: ss[node]=(relu.wt)*dv.
template <bool EMIT_S>
__global__ __launch_bounds__(256) void agg_k(const int* __restrict__ rowptr,
                                             const int* __restrict__ es,
                                             const float* __restrict__ dinv,
                                             const _Float16* __restrict__ hw,
                                             const float* __restrict__ b,
                                             _Float16* __restrict__ h,
                                             const float* __restrict__ wt,
                                             float* __restrict__ ss) {
    const int lane = threadIdx.x & 63;
    const int hf   = lane >> 5;          // 0: even edges, 1: odd edges
    const int cl   = lane & 31;          // channel-pair index (channels 2cl,2cl+1)
    int node = (blockIdx.x * 256 + threadIdx.x) >> 6;
    if (node >= N_NODES) return;
    int e0 = rowptr[node], e1 = rowptr[node + 1];
    float dv = dinv[node];
    const __half2* hw2 = (const __half2*)hw;   // row = 32 half2

    float ax, ay;  // channel-pair accumulator
    {   // self term: counted once (half 0 only; half 1 adds zero)
        float2 f = __half22float2(hw2[(size_t)node * 32 + cl]);
        ax = hf ? 0.0f : f.x;
        ay = hf ? 0.0f : f.y;
    }

    int e = e0;
    while ((e & 3) && e < e1) {  // align e to int4; single edges, half-0 only
        float2 f = __half22float2(hw2[(size_t)es[e] * 32 + cl]);
        if (!hf) { ax += f.x; ay += f.y; }
        ++e;
    }
    for (; e + 16 <= e1; e += 16) {   // 16 edges: 4 uniform idx loads, 8 gathers
        int4 m0 = *(const int4*)(es + e);
        int4 m1 = *(const int4*)(es + e + 4);
        int4 m2 = *(const int4*)(es + e + 8);
        int4 m3 = *(const int4*)(es + e + 12);
        int s0 = hf ? m0.y : m0.x;
        int s1 = hf ? m0.w : m0.z;
        int s2 = hf ? m1.y : m1.x;
        int s3 = hf ? m1.w : m1.z;
        int s4 = hf ? m2.y : m2.x;
        int s5 = hf ? m2.w : m2.z;
        int s6 = hf ? m3.y : m3.x;
        int s7 = hf ? m3.w : m3.z;
        float2 f0 = __half22float2(hw2[(size_t)s0 * 32 + cl]);
        float2 f1 = __half22float2(hw2[(size_t)s1 * 32 + cl]);
        float2 f2 = __half22float2(hw2[(size_t)s2 * 32 + cl]);
        float2 f3 = __half22float2(hw2[(size_t)s3 * 32 + cl]);
        float2 f4 = __half22float2(hw2[(size_t)s4 * 32 + cl]);
        float2 f5 = __half22float2(hw2[(size_t)s5 * 32 + cl]);
        float2 f6 = __half22float2(hw2[(size_t)s6 * 32 + cl]);
        float2 f7 = __half22float2(hw2[(size_t)s7 * 32 + cl]);
        ax += ((f0.x + f1.x) + (f2.x + f3.x)) + ((f4.x + f5.x) + (f6.x + f7.x));
        ay += ((f0.y + f1.y) + (f2.y + f3.y)) + ((f4.y + f5.y) + (f6.y + f7.y));
    }
    for (; e + 4 <= e1; e += 4) {     // 4 edges: 1 idx load, 2 gathers
        int4 m = *(const int4*)(es + e);
        int sA = hf ? m.y : m.x;
        int sB = hf ? m.w : m.z;
        float2 fA = __half22float2(hw2[(size_t)sA * 32 + cl]);
        float2 fB = __half22float2(hw2[(size_t)sB * 32 + cl]);
        ax += fA.x + fB.x;
        ay += fA.y + fB.y;
    }
    for (; e < e1; ++e) {             // tail singles, half-0 only
        float2 f = __half22float2(hw2[(size_t)es[e] * 32 + cl]);
        if (!hf) { ax += f.x; ay += f.y; }
    }

    // combine halves: both end with full sums
    ax += __shfl_xor(ax, 32);
    ay += __shfl_xor(ay, 32);

    float2 bb = ((const float2*)b)[cl];
    float r0 = fmaxf(bb.x + dv * ax, 0.0f);   // relu (layers 1 and 2)
    float r1 = fmaxf(bb.y + dv * ay, 0.0f);
    if constexpr (EMIT_S) {
        float2 ww = ((const float2*)wt)[cl];
        float d = r0 * ww.x + r1 * ww.y;
        for (int o = 1; o < 32; o <<= 1) d += __shfl_xor(d, o);  // intra-32 sum
        if (lane == 0) ss[node] = d * dv;
    } else {
        if (!hf) {
            __half2 hv = __floats2half2_rn(r0, r1);
            ((__half2*)(h + (size_t)node * HDIM))[cl] = hv;
        }
    }
}

// ---------------------------------------------------------------------------
// layer-3 scalar aggregation + fused mean-pool; 4 threads per node.
__global__ __launch_bounds__(256) void agg3s_k(const int* __restrict__ rowptr,
                                               const int* __restrict__ es,
                                               const float* __restrict__ dinv,
                                               const float* __restrict__ ss,
                                               const int* __restrict__ batch,
                                               const float* __restrict__ bc,
                                               float* __restrict__ gsum,
                                               float* __restrict__ gcnt) {
    int t = blockIdx.x * 256 + threadIdx.x;
    int i = t >> 2, q = t & 3;
    bool act = i < N_NODES;
    float contrib = 0.0f;
    int g = -1;
    if (act) {
        g = batch[i];
        float dv = dinv[i];
        int e0 = rowptr[i], len = rowptr[i + 1] - e0;
        int qa = e0 + ((len * q) >> 2);
        int qb = e0 + ((len * (q + 1)) >> 2);
        float acc = (q == 0) ? ss[i] : 0.0f;
#pragma unroll 4
        for (int e = qa; e < qb; ++e) acc += ss[es[e]];
        contrib = dv * acc + ((q == 0) ? bc[0] : 0.0f);
    }
    int g0 = __shfl(g, 0);
    bool uni = (__ballot(act && (g == g0)) == ~0ULL);
    if (uni) {
        for (int o = 32; o > 0; o >>= 1) contrib += __shfl_down(contrib, o);
        if ((threadIdx.x & 63) == 0) {
            atomicAdd(&gsum[g0], contrib);
            atomicAdd(&gcnt[g0], 16.0f);
        }
    } else if (act) {
        atomicAdd(&gsum[g], contrib);
        if (q == 0) atomicAdd(&gcnt[g], 1.0f);
    }
}

__global__ void final_k(float* __restrict__ out, const float* __restrict__ gsum,
                        const float* __restrict__ gcnt, const float* __restrict__ lb) {
    int g = blockIdx.x * blockDim.x + threadIdx.x;
    if (g < N_GRAPHS) out[g] = gsum[g] / fmaxf(gcnt[g], 1.0f) + lb[0];
}

// ---------------------------------------------------------------------------
extern "C" void kernel_launch(void* const* d_in, const int* in_sizes, int n_in,
                              void* d_out, int out_size, void* d_ws, size_t ws_size,
                              hipStream_t stream) {
    const float* x     = (const float*)d_in[0];
    const int*   eidx  = (const int*)d_in[1];   // [2, E] int32
    const int*   batch = (const int*)d_in[3];
    const float* W1 = (const float*)d_in[4];
    const float* b1 = (const float*)d_in[5];
    const float* W2 = (const float*)d_in[6];
    const float* b2 = (const float*)d_in[7];
    const float* W3 = (const float*)d_in[8];
    const float* b3 = (const float*)d_in[9];
    const float* lin_w = (const float*)d_in[10];
    const float* lin_b = (const float*)d_in[11];
    float* out = (float*)d_out;

    const int* src = eidx;
    const int* dst = eidx + N_EDGES;

    float*    ws     = (float*)d_ws;
    float*    dinv   = ws;                          // 100352 f
    int*      rowptr = (int*)(ws + 100352);         // 100352 i
    int*      cbase  = rowptr + 100352;             // 512
    int*      bsum   = cbase + 512;                 // 512
    int*      boff   = bsum + 512;                  // 512
    int*      H      = boff + 512;                  // 100352
    int*      goff   = H + 100352;                  // 100352
    int*      es     = goff + 100352;               // 1.6M i, 16B-aligned
    _Float16* bufH   = (_Float16*)(es + N_EDGES);   // 6.4M halfs gemm-out (128B-aligned)
    _Float16* bufF   = bufH + 6400000;              // 6.4M halfs agg1-out (fp16)
    float*    gsum   = (float*)(bufF + 6400000);    // 1024
    float*    gcnt   = gsum + 1024;                 // 1024
    float*    wt     = gcnt + 1024;                 // 128
    float*    bc     = wt + 128;                    // 16
    float*    ss     = bc + 16;                     // 100352   (~36 MB total)
    int*      eC     = (int*)bufH;                  // 1.6M i, aliases bufH

    // ---- precompute + CSR build (deterministic; zero global atomics) ----
    wtilde_k<<<5, 256, 0, stream>>>(W3, b3, lin_w, wt, bc, gsum, gcnt);
    coarse_hist_k<<<NBLK_C, 1024, 0, stream>>>(dst, H);
    scanA_k<<<NSCN, 256, 0, stream>>>(H, bsum);
    scanB_k<<<1, 1024, 0, stream>>>(bsum, boff);
    scanC_k<<<NSCN, 256, 0, stream>>>(H, boff, goff, cbase);
    coarse_scatter_k<<<NBLK_C, 1024, 0, stream>>>(src, dst, goff, eC);
    bucket_count_k<<<NCOARSE, 1024, 0, stream>>>(eC, cbase, rowptr, dinv);
    bucket_scatter_k<<<NCOARSE, 1024, 0, stream>>>(eC, cbase, rowptr, es);

    // ---- layer 1 (fp32 x in, fp16 h1 out) ----
    gemm_k<F_IN, float><<<1563, 256, 0, stream>>>(x, W1, dinv, bufH);
    agg_k<false><<<25000, 256, 0, stream>>>(rowptr, es, dinv, bufH, b1,
                                            bufF, nullptr, nullptr);
    // ---- layer 2 (fp16 h1 in; s fused into epilogue) ----
    gemm_k<HDIM, _Float16><<<1563, 256, 0, stream>>>(bufF, W2, dinv, bufH);
    agg_k<true><<<25000, 256, 0, stream>>>(rowptr, es, dinv, bufH, b2,
                                           nullptr, wt, ss);
    // ---- layer 3 scalar + fused pool ----
    agg3s_k<<<1563, 256, 0, stream>>>(rowptr, es, dinv, ss, batch, bc, gsum, gcnt);
    final_k<<<(N_GRAPHS + 255) / 256, 256, 0, stream>>>(out, gsum, gcnt, lin_b);
}